// Round 1
// baseline (425.122 us; speedup 1.0000x reference)
//
#include <hip/hip_runtime.h>

// PositionEnhancedLoss: f32 L1 loss split into 96x96 patch vs rest, weighted 0.5/0.5.
// x,y: [64,3,512,512] f32. position: [64,2] int (rows, cols). Output: 1 f32 scalar.

#define IMG    512
#define HALF   48
#define B_DIM  64
#define C_DIM  3
#define NELEM  (64u * 3u * 512u * 512u)      // 50331648
#define NV4    (NELEM / 4u)                  // 12582912
#define PER_IMG 786432u                      // 3*512*512

__device__ inline void crop_dim(int d, int& top, int& bot) {
    int t = d - HALF;
    int tr = max(-t, 0);
    t = max(t, 0);
    int b = d + HALF;
    int br = max(b - (IMG - 1), 0);
    b = min(b, IMG - 1);
    top = t - br;      // window [top, bot), width 96
    bot = b + tr;
}

// Setup: decode position (int32 or int64 memory layout), build per-batch windows,
// zero the double accumulators. Runs every call (ws is re-poisoned each launch).
__global__ void pel_setup(const int* __restrict__ pos32, double* acc, int4* wins) {
    __shared__ int is64_s;
    const int t = threadIdx.x;
    if (t == 0) {
        // int64 little-endian => every odd 32-bit word is the (zero) high half.
        // int32 => odd words are random col positions in [0,512): all-zero is ~impossible.
        int allzero = 1;
        for (int i = 1; i < 2 * B_DIM; i += 2) allzero &= (pos32[i] == 0);
        is64_s = allzero;
        acc[0] = 0.0;   // patch_sum
        acc[1] = 0.0;   // total_sum
    }
    __syncthreads();
    const int is64 = is64_s;
    if (t < B_DIM) {
        int r, c;
        if (is64) {
            const long long* p64 = (const long long*)pos32;
            r = (int)p64[2 * t];
            c = (int)p64[2 * t + 1];
        } else {
            r = pos32[2 * t];
            c = pos32[2 * t + 1];
        }
        int ty, by, tx, bx;
        crop_dim(r, ty, by);
        crop_dim(c, tx, bx);
        wins[t] = make_int4(ty, by, tx, bx);
    }
}

__global__ __launch_bounds__(256) void pel_main(const float4* __restrict__ x,
                                                const float4* __restrict__ y,
                                                const int4* __restrict__ wins,
                                                double* acc) {
    const unsigned stride = gridDim.x * blockDim.x;
    float psum = 0.0f, tsum = 0.0f;
    for (unsigned i = blockIdx.x * blockDim.x + threadIdx.x; i < NV4; i += stride) {
        const unsigned e = i * 4u;                 // flat element index
        const unsigned b = e / PER_IMG;            // batch (magic-mul)
        const int r = (int)((e >> 9) & 511u);      // row within image
        const int c = (int)(e & 511u);             // col of lane's first element
        const float4 xv = x[i];
        const float4 yv = y[i];
        const float a0 = fabsf(xv.x - yv.x);
        const float a1 = fabsf(xv.y - yv.y);
        const float a2 = fabsf(xv.z - yv.z);
        const float a3 = fabsf(xv.w - yv.w);
        tsum += (a0 + a1) + (a2 + a3);
        const int4 w = wins[b];                    // tiny, L1-resident
        if (r >= w.x && r < w.y) {
            float p = 0.0f;
            if (c     >= w.z && c     < w.w) p += a0;
            if (c + 1 >= w.z && c + 1 < w.w) p += a1;
            if (c + 2 >= w.z && c + 2 < w.w) p += a2;
            if (c + 3 >= w.z && c + 3 < w.w) p += a3;
            psum += p;
        }
    }
    // wave-64 butterfly reduce
    #pragma unroll
    for (int off = 32; off > 0; off >>= 1) {
        psum += __shfl_down(psum, off);
        tsum += __shfl_down(tsum, off);
    }
    __shared__ float sp[4], st[4];
    const int wave = threadIdx.x >> 6;
    const int lane = threadIdx.x & 63;
    if (lane == 0) { sp[wave] = psum; st[wave] = tsum; }
    __syncthreads();
    if (threadIdx.x == 0) {
        const float P = (sp[0] + sp[1]) + (sp[2] + sp[3]);
        const float T = (st[0] + st[1]) + (st[2] + st[3]);
        atomicAdd(&acc[0], (double)P);
        atomicAdd(&acc[1], (double)T);
    }
}

__global__ void pel_final(const double* __restrict__ acc, float* __restrict__ out) {
    const double patch_sum = acc[0];
    const double total_sum = acc[1];
    const double rest_sum = total_sum - patch_sum;
    const double patch_numel = (double)B_DIM * C_DIM * 96.0 * 96.0;     // 1769472
    const double total_numel = (double)NELEM;                            // 50331648
    const double rest_numel = total_numel - patch_numel;
    const double res = (rest_sum / rest_numel) * 0.5 + 0.5 * (patch_sum / patch_numel);
    out[0] = (float)res;
}

extern "C" void kernel_launch(void* const* d_in, const int* in_sizes, int n_in,
                              void* d_out, int out_size, void* d_ws, size_t ws_size,
                              hipStream_t stream) {
    const float* x = (const float*)d_in[0];
    const float* y = (const float*)d_in[1];
    const int*   pos = (const int*)d_in[2];
    double* acc = (double*)d_ws;                    // 2 doubles
    int4*   wins = (int4*)((char*)d_ws + 16);       // 64 windows

    pel_setup<<<1, 64, 0, stream>>>(pos, acc, wins);
    pel_main<<<2048, 256, 0, stream>>>((const float4*)x, (const float4*)y, wins, acc);
    pel_final<<<1, 1, 0, stream>>>(acc, (float*)d_out);
}

// Round 2
// 403.056 us; speedup vs baseline: 1.0547x; 1.0547x over previous
//
#include <hip/hip_runtime.h>

// PositionEnhancedLoss: f32 L1 loss split into 96x96 patch vs rest, weighted 0.5/0.5.
// x,y: [64,3,512,512] f32. position: [64,2] int64 (rows, cols). Output: 1 f32 scalar.
//
// R2: latency-bound fix — compile-time stride, 8-wide unrolled load batches
// (16 outstanding 16B loads/wave), wins in LDS, per-block partials (no atomics).

#define IMG     512
#define HALF    48
#define B_DIM   64
#define NELEM   (64u * 3u * 512u * 512u)     // 50331648
#define NV4     (NELEM / 4u)                 // 12582912 float4s
#define THREADS 256
#define BLOCKS  2048
#define STRIDE  (BLOCKS * THREADS)           // 524288
#define ITERS   (NV4 / STRIDE)               // 24, exact
#define UNROLL  8
#define OUTER   (ITERS / UNROLL)             // 3
#define IMG_V4  196608u                      // 3*512*512/4, float4s per image

__device__ inline void crop_dim(int d, int& top, int& bot) {
    int t = d - HALF;
    int tr = max(-t, 0);
    t = max(t, 0);
    int b = d + HALF;
    int br = max(b - (IMG - 1), 0);
    b = min(b, IMG - 1);
    top = t - br;      // window [top, bot), width 96
    bot = b + tr;
}

// Decode position (int32 or int64 layout) -> 64 windows in d_ws.
__global__ void pel_setup(const int* __restrict__ pos32, int4* wins) {
    __shared__ int is64_s;
    const int t = threadIdx.x;
    if (t == 0) {
        // int64 LE => odd 32-bit words are zero high-halves; int32 random cols ~never all zero.
        int allzero = 1;
        for (int i = 1; i < 2 * B_DIM; i += 2) allzero &= (pos32[i] == 0);
        is64_s = allzero;
    }
    __syncthreads();
    if (t < B_DIM) {
        int r, c;
        if (is64_s) {
            const long long* p64 = (const long long*)pos32;
            r = (int)p64[2 * t];
            c = (int)p64[2 * t + 1];
        } else {
            r = pos32[2 * t];
            c = pos32[2 * t + 1];
        }
        int ty, by, tx, bx;
        crop_dim(r, ty, by);
        crop_dim(c, tx, bx);
        wins[t] = make_int4(ty, by, tx, bx);
    }
}

__global__ __launch_bounds__(THREADS) void pel_main(const float4* __restrict__ x,
                                                    const float4* __restrict__ y,
                                                    const int4* __restrict__ wins,
                                                    float2* __restrict__ partials) {
    __shared__ int4 s_wins[B_DIM];
    if (threadIdx.x < B_DIM) s_wins[threadIdx.x] = wins[threadIdx.x];
    __syncthreads();

    const unsigned base = blockIdx.x * THREADS + threadIdx.x;
    float psum = 0.0f, tsum = 0.0f;

    #pragma unroll 1
    for (int o = 0; o < OUTER; ++o) {
        float4 xv[UNROLL], yv[UNROLL];
        #pragma unroll
        for (int u = 0; u < UNROLL; ++u) {
            const unsigned i = base + (unsigned)(o * UNROLL + u) * STRIDE;
            xv[u] = x[i];
            yv[u] = y[i];
        }
        #pragma unroll
        for (int u = 0; u < UNROLL; ++u) {
            const unsigned i = base + (unsigned)(o * UNROLL + u) * STRIDE;
            const float a0 = fabsf(xv[u].x - yv[u].x);
            const float a1 = fabsf(xv[u].y - yv[u].y);
            const float a2 = fabsf(xv[u].z - yv[u].z);
            const float a3 = fabsf(xv[u].w - yv[u].w);
            tsum += (a0 + a1) + (a2 + a3);
            const unsigned b = i / IMG_V4;           // batch
            const int r = (int)((i >> 7) & 511u);    // row
            const int c = (int)((i & 127u) << 2);    // col of first element
            const int4 w = s_wins[b];
            if ((unsigned)(r - w.x) < 96u) {
                float p = 0.0f;
                p += ((unsigned)(c     - w.z) < 96u) ? a0 : 0.0f;
                p += ((unsigned)(c + 1 - w.z) < 96u) ? a1 : 0.0f;
                p += ((unsigned)(c + 2 - w.z) < 96u) ? a2 : 0.0f;
                p += ((unsigned)(c + 3 - w.z) < 96u) ? a3 : 0.0f;
                psum += p;
            }
        }
    }

    // wave-64 butterfly reduce
    #pragma unroll
    for (int off = 32; off > 0; off >>= 1) {
        psum += __shfl_down(psum, off);
        tsum += __shfl_down(tsum, off);
    }
    __shared__ float sp[4], st[4];
    const int wave = threadIdx.x >> 6;
    if ((threadIdx.x & 63) == 0) { sp[wave] = psum; st[wave] = tsum; }
    __syncthreads();
    if (threadIdx.x == 0) {
        partials[blockIdx.x] = make_float2((sp[0] + sp[1]) + (sp[2] + sp[3]),
                                           (st[0] + st[1]) + (st[2] + st[3]));
    }
}

__global__ __launch_bounds__(256) void pel_final(const float2* __restrict__ partials,
                                                 float* __restrict__ out) {
    double psum = 0.0, tsum = 0.0;
    for (int i = threadIdx.x; i < BLOCKS; i += 256) {
        const float2 v = partials[i];
        psum += (double)v.x;
        tsum += (double)v.y;
    }
    #pragma unroll
    for (int off = 32; off > 0; off >>= 1) {
        psum += __shfl_down(psum, off);
        tsum += __shfl_down(tsum, off);
    }
    __shared__ double sp[4], st[4];
    const int wave = threadIdx.x >> 6;
    if ((threadIdx.x & 63) == 0) { sp[wave] = psum; st[wave] = tsum; }
    __syncthreads();
    if (threadIdx.x == 0) {
        const double patch_sum = (sp[0] + sp[1]) + (sp[2] + sp[3]);
        const double total_sum = (st[0] + st[1]) + (st[2] + st[3]);
        const double rest_sum = total_sum - patch_sum;
        const double patch_numel = 64.0 * 3.0 * 96.0 * 96.0;      // 1769472
        const double rest_numel = (double)NELEM - patch_numel;
        out[0] = (float)((rest_sum / rest_numel) * 0.5 + 0.5 * (patch_sum / patch_numel));
    }
}

extern "C" void kernel_launch(void* const* d_in, const int* in_sizes, int n_in,
                              void* d_out, int out_size, void* d_ws, size_t ws_size,
                              hipStream_t stream) {
    const float* x = (const float*)d_in[0];
    const float* y = (const float*)d_in[1];
    const int*   pos = (const int*)d_in[2];
    int4*   wins     = (int4*)d_ws;                       // 64 * 16 B
    float2* partials = (float2*)((char*)d_ws + 1024);     // 2048 * 8 B

    pel_setup<<<1, 64, 0, stream>>>(pos, wins);
    pel_main<<<BLOCKS, THREADS, 0, stream>>>((const float4*)x, (const float4*)y, wins, partials);
    pel_final<<<1, 256, 0, stream>>>(partials, (float*)d_out);
}

// Round 4
// 399.750 us; speedup vs baseline: 1.0635x; 1.0083x over previous
//
#include <hip/hip_runtime.h>

// PositionEnhancedLoss: f32 L1 loss split into 96x96 patch vs rest, weighted 0.5/0.5.
// x,y: [64,3,512,512] f32. position: [64,2] int64 (rows, cols). Output: 1 f32 scalar.
//
// R3 (resubmit; R3 bench never ran — broker timeout): force 16 outstanding
// loads/wave via sched_barrier(0) between load batch and compute batch
// (R2's batch was collapsed by the scheduler: VGPR=48, ~2 loads in flight).

#define IMG     512
#define HALF    48
#define B_DIM   64
#define NELEM   (64u * 3u * 512u * 512u)     // 50331648
#define NV4     (NELEM / 4u)                 // 12582912 float4s
#define THREADS 256
#define BLOCKS  2048
#define STRIDE  (BLOCKS * THREADS)           // 524288
#define ITERS   (NV4 / STRIDE)               // 24, exact
#define UNROLL  8
#define OUTER   (ITERS / UNROLL)             // 3
#define IMG_V4  196608u                      // 3*512*512/4, float4s per image

__device__ inline void crop_dim(int d, int& top, int& bot) {
    int t = d - HALF;
    int tr = max(-t, 0);
    t = max(t, 0);
    int b = d + HALF;
    int br = max(b - (IMG - 1), 0);
    b = min(b, IMG - 1);
    top = t - br;      // window [top, bot), width 96
    bot = b + tr;
}

// Decode position (int32 or int64 layout) -> 64 windows in d_ws.
__global__ void pel_setup(const int* __restrict__ pos32, int4* wins) {
    __shared__ int is64_s;
    const int t = threadIdx.x;
    if (t == 0) {
        // int64 LE => odd 32-bit words are zero high-halves; int32 random cols ~never all zero.
        int allzero = 1;
        for (int i = 1; i < 2 * B_DIM; i += 2) allzero &= (pos32[i] == 0);
        is64_s = allzero;
    }
    __syncthreads();
    if (t < B_DIM) {
        int r, c;
        if (is64_s) {
            const long long* p64 = (const long long*)pos32;
            r = (int)p64[2 * t];
            c = (int)p64[2 * t + 1];
        } else {
            r = pos32[2 * t];
            c = pos32[2 * t + 1];
        }
        int ty, by, tx, bx;
        crop_dim(r, ty, by);
        crop_dim(c, tx, bx);
        wins[t] = make_int4(ty, by, tx, bx);
    }
}

__global__ __launch_bounds__(THREADS) void pel_main(const float4* __restrict__ x,
                                                    const float4* __restrict__ y,
                                                    const int4* __restrict__ wins,
                                                    float2* __restrict__ partials) {
    __shared__ int4 s_wins[B_DIM];
    if (threadIdx.x < B_DIM) s_wins[threadIdx.x] = wins[threadIdx.x];
    __syncthreads();

    const unsigned base = blockIdx.x * THREADS + threadIdx.x;
    float psum = 0.0f, tsum = 0.0f;

    #pragma unroll 1
    for (int o = 0; o < OUTER; ++o) {
        float4 xv[UNROLL], yv[UNROLL];
        // Phase 1: issue all 16 loads.
        #pragma unroll
        for (int u = 0; u < UNROLL; ++u) {
            const unsigned i = base + (unsigned)(o * UNROLL + u) * STRIDE;
            xv[u] = x[i];
            yv[u] = y[i];
        }
        // Hard fence: scheduler may not sink loads below / hoist compute above.
        __builtin_amdgcn_sched_barrier(0);
        // Phase 2: consume in issue order (incremental vmcnt waits).
        #pragma unroll
        for (int u = 0; u < UNROLL; ++u) {
            const unsigned i = base + (unsigned)(o * UNROLL + u) * STRIDE;
            const float a0 = fabsf(xv[u].x - yv[u].x);
            const float a1 = fabsf(xv[u].y - yv[u].y);
            const float a2 = fabsf(xv[u].z - yv[u].z);
            const float a3 = fabsf(xv[u].w - yv[u].w);
            tsum += (a0 + a1) + (a2 + a3);
            const unsigned b = i / IMG_V4;           // batch
            const int r = (int)((i >> 7) & 511u);    // row
            const int c = (int)((i & 127u) << 2);    // col of first element
            const int4 w = s_wins[b];
            if ((unsigned)(r - w.x) < 96u) {
                float p = 0.0f;
                p += ((unsigned)(c     - w.z) < 96u) ? a0 : 0.0f;
                p += ((unsigned)(c + 1 - w.z) < 96u) ? a1 : 0.0f;
                p += ((unsigned)(c + 2 - w.z) < 96u) ? a2 : 0.0f;
                p += ((unsigned)(c + 3 - w.z) < 96u) ? a3 : 0.0f;
                psum += p;
            }
        }
    }

    // wave-64 butterfly reduce
    #pragma unroll
    for (int off = 32; off > 0; off >>= 1) {
        psum += __shfl_down(psum, off);
        tsum += __shfl_down(tsum, off);
    }
    __shared__ float sp[4], st[4];
    const int wave = threadIdx.x >> 6;
    if ((threadIdx.x & 63) == 0) { sp[wave] = psum; st[wave] = tsum; }
    __syncthreads();
    if (threadIdx.x == 0) {
        partials[blockIdx.x] = make_float2((sp[0] + sp[1]) + (sp[2] + sp[3]),
                                           (st[0] + st[1]) + (st[2] + st[3]));
    }
}

__global__ __launch_bounds__(256) void pel_final(const float2* __restrict__ partials,
                                                 float* __restrict__ out) {
    double psum = 0.0, tsum = 0.0;
    for (int i = threadIdx.x; i < BLOCKS; i += 256) {
        const float2 v = partials[i];
        psum += (double)v.x;
        tsum += (double)v.y;
    }
    #pragma unroll
    for (int off = 32; off > 0; off >>= 1) {
        psum += __shfl_down(psum, off);
        tsum += __shfl_down(tsum, off);
    }
    __shared__ double sp[4], st[4];
    const int wave = threadIdx.x >> 6;
    if ((threadIdx.x & 63) == 0) { sp[wave] = psum; st[wave] = tsum; }
    __syncthreads();
    if (threadIdx.x == 0) {
        const double patch_sum = (sp[0] + sp[1]) + (sp[2] + sp[3]);
        const double total_sum = (st[0] + st[1]) + (st[2] + st[3]);
        const double rest_sum = total_sum - patch_sum;
        const double patch_numel = 64.0 * 3.0 * 96.0 * 96.0;      // 1769472
        const double rest_numel = (double)NELEM - patch_numel;
        out[0] = (float)((rest_sum / rest_numel) * 0.5 + 0.5 * (patch_sum / patch_numel));
    }
}

extern "C" void kernel_launch(void* const* d_in, const int* in_sizes, int n_in,
                              void* d_out, int out_size, void* d_ws, size_t ws_size,
                              hipStream_t stream) {
    const float* x = (const float*)d_in[0];
    const float* y = (const float*)d_in[1];
    const int*   pos = (const int*)d_in[2];
    int4*   wins     = (int4*)d_ws;                       // 64 * 16 B
    float2* partials = (float2*)((char*)d_ws + 1024);     // 2048 * 8 B

    pel_setup<<<1, 64, 0, stream>>>(pos, wins);
    pel_main<<<BLOCKS, THREADS, 0, stream>>>((const float4*)x, (const float4*)y, wins, partials);
    pel_final<<<1, 256, 0, stream>>>(partials, (float*)d_out);
}